// Round 20
// baseline (87.237 us; speedup 1.0000x reference)
//
#include <hip/hip_runtime.h>
#include <hip/hip_bf16.h>
#include <stdint.h>

// Problem constants (from reference)
#define M_TOTAL 131072
#define K_DIM   512
#define N_RANK  256
#define NSEG    1024
#define KC      64              // k-chunk staged in LDS (64 bf16 per row)
#define NKC     (K_DIM / KC)    // 8
#define BM      128             // rows per block
#define NBLK    (M_TOTAL / BM)  // 1024 fused blocks
#define NB64    (M_TOTAL / 64)  // 2048 virtual 64-row groups (pass2 granularity)

typedef __attribute__((ext_vector_type(8))) short bf16x8;
typedef __attribute__((ext_vector_type(4))) float f32x4;

// Raw barrier: lgkmcnt(0) makes my ds_writes visible, vmcnt NOT drained.
#define BAR() do { \
    asm volatile("s_waitcnt lgkmcnt(0)" ::: "memory"); \
    __builtin_amdgcn_s_barrier(); \
} while (0)

__device__ inline short f2b(float f) {
    __hip_bfloat16 h = __float2bfloat16(f);
    return __builtin_bit_cast(short, h);
}

// fast tanh: t = sign(z) * (1 - 2/(e^{2|z|}+1))
__device__ inline float fast_tanh(float z) {
    float e = __expf(2.0f * fabsf(z));
    return copysignf(1.0f - 2.0f / (e + 1.0f), z);
}

// Kernel 1: init out to 1.0 (segment_prod identity for empty segments)
//           + convert W to bf16 in ws
__global__ void prep_kernel(const float* __restrict__ W,
                            __hip_bfloat16* __restrict__ Wb,
                            float* __restrict__ out) {
    int i = blockIdx.x * 256 + threadIdx.x;
    out[i] = 1.0f;
    if (i < N_RANK * K_DIM) Wb[i] = __float2bfloat16(W[i]);
}

// Kernel 2 (pass 1): fused GEMM + bias + tanh + in-register segmented product.
//
// R20 = R19 + K-chunk START de-phasing. Diagnosis: per-CU chunk slot ~6k cy
// vs ~3k cy summed pipe demand -- the two co-resident blocks run the same
// barrier-phased schedule IN PHASE, so staging bursts (HBM) and compute
// phases (LDS/MFMA) collide instead of interleaving. Fix: the K-sum is
// commutative, so half the blocks start their chunk rotation at 4
// (START = ((bid>>8)&1)*4; co-resident pairs {c, c+256} under round-robin
// dispatch get opposite phase). Buffer parity preserved (START even).
//
// Structure pins (measured): 8-wave col-slice is the ONLY geometry fitting
// the (512,4) 128-reg cap (R13/R14/R17 spilled); KC=64 beats 128 (R18
// +16us); BM=128 beats 64 (R15 +20us); bf16 cvt ONCE at stage-write (R12
// -7.4us); single barrier per chunk (R11 -6.7us); B-loads oldest in VMEM
// queue -> counted B-use wait, G-loads newest -> fly across compute (R9).
__launch_bounds__(512, 4)   // reg cap 128; spill canary = WRITE_SIZE balloon
__global__ void fused_kernel(const float* __restrict__ x,
                             const __hip_bfloat16* __restrict__ Wb,
                             const float* __restrict__ bias,
                             const int* __restrict__ seg,
                             float* __restrict__ out,
                             float* __restrict__ partial) {
    const int tid  = threadIdx.x;
    const int wave = tid >> 6;        // 0..7 = column-slice
    const int lane = tid & 63;
    const int l16  = lane & 15;
    const int g    = lane >> 4;       // 0..3 (k-group / row-group)
    const int bid  = blockIdx.x;
    const int m0   = bid * BM;
    const int n0   = wave * 32;

    // chunk rotation start: de-phases co-resident blocks' staging bursts
    const int START = ((bid >> 8) & 1) * 4;

    // LDS: A double-buffer, 2 x (128 rows x 128B bf16) = 32 KB.
    __shared__ alignas(16) char smem[32768];

    // ---- staging geometry: thread covers one 16B f32 slot, 4 slabs ----
    const int srow = tid >> 4;        // 0..31
    const int sc16 = tid & 15;

    f32x4 acc[8][2] = {};             // [m-frag][n-frag]
    f32x4 sg[4];                      // staged f32 for next chunk

    #define STAGE_LOAD(kc_)                                                   \
        do {                                                                  \
            _Pragma("unroll")                                                 \
            for (int it = 0; it < 4; ++it)                                    \
                sg[it] = *reinterpret_cast<const f32x4*>(                     \
                    x + (size_t)(m0 + it * 32 + srow) * K_DIM + (kc_) * KC + sc16 * 4); \
        } while (0)

    #define STAGE_WRITE(buf_)                                                 \
        do {                                                                  \
            _Pragma("unroll")                                                 \
            for (int it = 0; it < 4; ++it) {                                  \
                const int row = it * 32 + srow;                               \
                short4 p;                                                     \
                p.x = f2b(sg[it][0]); p.y = f2b(sg[it][1]);                   \
                p.z = f2b(sg[it][2]); p.w = f2b(sg[it][3]);                   \
                *reinterpret_cast<short4*>(smem + (buf_) * 16384 + row * 128  \
                    + ((sc16 * 8) ^ ((row & 7) << 4))) = p;                   \
            }                                                                 \
        } while (0)

    // ---- prologue: stage chunk START into buf 0 ----
    STAGE_LOAD(START);
    asm volatile("s_waitcnt vmcnt(0)" ::: "memory");
    STAGE_WRITE(0);

    // ---- K loop: 8 chunks of 64 (rotated by START), ONE barrier each ----
    #pragma unroll
    for (int kc = 0; kc < NKC; ++kc) {
        const int ck = (kc + START) & 7;     // logical chunk this iteration
        BAR();   // buf[kc&1] visible to all; buf[(kc+1)&1] free to write

        // 1) B fragments (L2-resident, 4 loads/wave) -- oldest in VMEM queue
        bf16x8 bfr[2][2];
        #pragma unroll
        for (int s = 0; s < 2; ++s)
            #pragma unroll
            for (int j = 0; j < 2; ++j)
                bfr[s][j] = *reinterpret_cast<const bf16x8*>(
                    Wb + (size_t)(n0 + j * 16 + l16) * K_DIM + ck * KC + s * 32 + g * 8);
        __builtin_amdgcn_sched_barrier(0);   // pin: B-loads stay above G-loads

        // 2) issue G loads for the next logical chunk (newest; fly across)
        if (kc + 1 < NKC) STAGE_LOAD((ck + 1) & 7);
        __builtin_amdgcn_sched_barrier(0);   // pin: G-loads stay above compute

        // 3) compute chunk ck from LDS buf kc&1 (A-frag = 1 ds_read_b128;
        //    compiler's B-use wait = counted vmcnt, G stays in flight)
        const int bufb = (kc & 1) * 16384;
        __builtin_amdgcn_s_setprio(1);
        #pragma unroll
        for (int s = 0; s < 2; ++s) {
            #pragma unroll
            for (int i = 0; i < 8; ++i) {
                const int row = i * 16 + l16;
                bf16x8 av = *reinterpret_cast<const bf16x8*>(
                    smem + bufb + row * 128 + ((s * 64 + g * 16) ^ ((row & 7) << 4)));
                #pragma unroll
                for (int j = 0; j < 2; ++j)
                    acc[i][j] = __builtin_amdgcn_mfma_f32_16x16x32_bf16(
                        av, bfr[s][j], acc[i][j], 0, 0, 0);
            }
        }
        __builtin_amdgcn_s_setprio(0);

        // 4) convert + write the prefetched chunk (loads had whole compute)
        if (kc + 1 < NKC) {
            asm volatile("s_waitcnt vmcnt(0)" ::: "memory");
            STAGE_WRITE((kc + 1) & 1);
        }
    }
    #undef STAGE_LOAD
    #undef STAGE_WRITE

    // ---- bias + tanh in regs ----
    // D layout: col = lane&15, row(within 16x16) = (lane>>4)*4 + r
    #pragma unroll
    for (int j = 0; j < 2; ++j) {
        const float bj = bias[n0 + j * 16 + l16];
        #pragma unroll
        for (int i = 0; i < 8; ++i)
            #pragma unroll
            for (int r = 0; r < 4; ++r)
                acc[i][j][r] = fast_tanh(acc[i][j][r] + bj);
    }

    // ---- in-register segmented product, per 64-row half h ----
    // Virtual 64-row group vb = bid*2 + h keeps partial/pass2 layout stable.
    #pragma unroll
    for (int h = 0; h < 2; ++h) {
        const int vb     = bid * 2 + h;
        const int myseg  = seg[m0 + h * 64 + lane];
        const int prevsg = (lane == 0) ? (myseg ^ 1) : seg[m0 + h * 64 + lane - 1];
        uint64_t m = __ballot(myseg != prevsg);              // run-start bits

        while (m) {
            const int start = (int)__builtin_ctzll(m);
            m &= m - 1;
            const int end = m ? (int)__builtin_ctzll(m) : 64;
            const int s   = __shfl(myseg, start);            // run's segment id

            float p[2] = {1.0f, 1.0f};
            #pragma unroll
            for (int i2 = 0; i2 < 4; ++i2)
                #pragma unroll
                for (int r = 0; r < 4; ++r) {
                    const int row = i2 * 16 + g * 4 + r;     // row within half
                    const bool in = (row >= start) && (row < end);
                    #pragma unroll
                    for (int j = 0; j < 2; ++j)
                        p[j] *= in ? acc[h * 4 + i2][j][r] : 1.0f;
                }
            #pragma unroll
            for (int j = 0; j < 2; ++j) {
                p[j] *= __shfl_xor(p[j], 16);
                p[j] *= __shfl_xor(p[j], 32);
            }
            if (g == 0) {
                #pragma unroll
                for (int j = 0; j < 2; ++j) {
                    const int col = n0 + j * 16 + l16;
                    if (start == 0)
                        partial[(size_t)(vb * 2 + 0) * N_RANK + col] = p[j];
                    else if (end == 64)
                        partial[(size_t)(vb * 2 + 1) * N_RANK + col] = p[j];
                    else
                        out[(size_t)s * N_RANK + col] = p[j]; // interior: exclusive
                }
            }
        }
    }
}

// Kernel 3 (pass 2): combine boundary partials over 64-row groups (b = vb).
// Group b owns boundary segment s iff s first appears in group b. Interior
// segments were stored by pass 1; empty segments stay 1.0.
__global__ void pass2_kernel(const int* __restrict__ seg,
                             const float* __restrict__ partial,
                             float* __restrict__ out) {
    const int b   = blockIdx.x;
    const int col = threadIdx.x;      // 0..255
    const int sF    = seg[b * 64];
    const int sL    = seg[b * 64 + 63];
    const int prevL = (b == 0) ? -1 : seg[b * 64 - 1];

    if (prevL < sF) {                 // b owns its first segment
        float p = partial[(size_t)(b * 2 + 0) * N_RANK + col];
        for (int b2 = b + 1; b2 < NB64 && seg[b2 * 64] == sF; ++b2)
            p *= partial[(size_t)(b2 * 2 + 0) * N_RANK + col];
        out[(size_t)sF * N_RANK + col] = p;
    }
    if (sL != sF) {                   // b always owns sL when sL != sF
        float p = partial[(size_t)(b * 2 + 1) * N_RANK + col];
        for (int b2 = b + 1; b2 < NB64 && seg[b2 * 64] == sL; ++b2)
            p *= partial[(size_t)(b2 * 2 + 0) * N_RANK + col];
        out[(size_t)sL * N_RANK + col] = p;
    }
}

extern "C" void kernel_launch(void* const* d_in, const int* in_sizes, int n_in,
                              void* d_out, int out_size, void* d_ws, size_t ws_size,
                              hipStream_t stream) {
    const float* x   = (const float*)d_in[0];
    const float* W   = (const float*)d_in[1];
    const float* b   = (const float*)d_in[2];
    const int*   seg = (const int*)d_in[3];
    float*       out = (float*)d_out;
    __hip_bfloat16* Wb = (__hip_bfloat16*)d_ws;                       // 256 KB
    float* partial = (float*)((char*)d_ws + (1 << 20));               // 4 MB @ +1MB

    prep_kernel<<<(NSEG * N_RANK) / 256, 256, 0, stream>>>(W, Wb, out);
    fused_kernel<<<NBLK, 512, 0, stream>>>(x, Wb, b, seg, out, partial);
    pass2_kernel<<<NB64, 256, 0, stream>>>(seg, partial, out);
}

// Round 21
// 81.106 us; speedup vs baseline: 1.0756x; 1.0756x over previous
//
#include <hip/hip_runtime.h>
#include <hip/hip_bf16.h>
#include <stdint.h>

// Problem constants (from reference)
#define M_TOTAL 131072
#define K_DIM   512
#define N_RANK  256
#define NSEG    1024
#define KC      64              // k-chunk staged in LDS (64 bf16 per row)
#define NKC     (K_DIM / KC)    // 8
#define BM      128             // rows per block
#define NBLK    (M_TOTAL / BM)  // 1024 fused blocks
#define NB64    (M_TOTAL / 64)  // 2048 virtual 64-row groups (pass2 granularity)

typedef __attribute__((ext_vector_type(8))) short bf16x8;
typedef __attribute__((ext_vector_type(4))) float f32x4;

// Raw barrier: lgkmcnt(0) makes my ds_writes visible, vmcnt NOT drained.
#define BAR() do { \
    asm volatile("s_waitcnt lgkmcnt(0)" ::: "memory"); \
    __builtin_amdgcn_s_barrier(); \
} while (0)

__device__ inline short f2b(float f) {
    __hip_bfloat16 h = __float2bfloat16(f);
    return __builtin_bit_cast(short, h);
}

// fast tanh: t = sign(z) * (1 - 2/(e^{2|z|}+1))
__device__ inline float fast_tanh(float z) {
    float e = __expf(2.0f * fabsf(z));
    return copysignf(1.0f - 2.0f / (e + 1.0f), z);
}

// Kernel 1: init out to 1.0 (segment_prod identity for empty segments)
//           + convert W to bf16 in ws
__global__ void prep_kernel(const float* __restrict__ W,
                            __hip_bfloat16* __restrict__ Wb,
                            float* __restrict__ out) {
    int i = blockIdx.x * 256 + threadIdx.x;
    out[i] = 1.0f;
    if (i < N_RANK * K_DIM) Wb[i] = __float2bfloat16(W[i]);
}

// Kernel 2 (pass 1): fused GEMM + bias + tanh + in-register segmented product.
//
// R21 = R19 verbatim (best measured: 80.7 us). R20's chunk de-phasing
// REGRESSED (+6.5us): in-phase execution gives all blocks L2-temporal
// locality on the shared W chunk; staggering split it. Reverted.
//
// Structure pins (measured over R1-R20):
//  - 8-wave col-slice is the ONLY geometry fitting the (512,4) 128-reg cap
//    (R13/R14/R17 all spilled: VGPR=64 + scratch-traffic balloon).
//  - KC=64 beats 128 (R18 +16us); BM=128 beats 64 (R15 +20us).
//  - bf16 converted ONCE at stage-write (R12 -7.4us vs read-time cvt).
//  - Single barrier per chunk (R11 -6.7us vs barrier pair).
//  - B-loads FIRST (oldest in VMEM queue -> counted B-use wait), G-loads
//    after (newest -> fly across compute) (R9 -5us).
//  - Mid-chunk G-drain placement: null (R16). De-phasing: hurts (R20).
//  - setprio around MFMA: ~free, kept (R19).
__launch_bounds__(512, 4)   // reg cap 128; spill canary = WRITE_SIZE balloon
__global__ void fused_kernel(const float* __restrict__ x,
                             const __hip_bfloat16* __restrict__ Wb,
                             const float* __restrict__ bias,
                             const int* __restrict__ seg,
                             float* __restrict__ out,
                             float* __restrict__ partial) {
    const int tid  = threadIdx.x;
    const int wave = tid >> 6;        // 0..7 = column-slice
    const int lane = tid & 63;
    const int l16  = lane & 15;
    const int g    = lane >> 4;       // 0..3 (k-group / row-group)
    const int bid  = blockIdx.x;
    const int m0   = bid * BM;
    const int n0   = wave * 32;

    // LDS: A double-buffer, 2 x (128 rows x 128B bf16) = 32 KB.
    __shared__ alignas(16) char smem[32768];

    // ---- staging geometry: thread covers one 16B f32 slot, 4 slabs ----
    const int srow = tid >> 4;        // 0..31
    const int sc16 = tid & 15;

    f32x4 acc[8][2] = {};             // [m-frag][n-frag]
    f32x4 sg[4];                      // staged f32 for next chunk

    #define STAGE_LOAD(kc_)                                                   \
        do {                                                                  \
            _Pragma("unroll")                                                 \
            for (int it = 0; it < 4; ++it)                                    \
                sg[it] = *reinterpret_cast<const f32x4*>(                     \
                    x + (size_t)(m0 + it * 32 + srow) * K_DIM + (kc_) * KC + sc16 * 4); \
        } while (0)

    #define STAGE_WRITE(buf_)                                                 \
        do {                                                                  \
            _Pragma("unroll")                                                 \
            for (int it = 0; it < 4; ++it) {                                  \
                const int row = it * 32 + srow;                               \
                short4 p;                                                     \
                p.x = f2b(sg[it][0]); p.y = f2b(sg[it][1]);                   \
                p.z = f2b(sg[it][2]); p.w = f2b(sg[it][3]);                   \
                *reinterpret_cast<short4*>(smem + (buf_) * 16384 + row * 128  \
                    + ((sc16 * 8) ^ ((row & 7) << 4))) = p;                   \
            }                                                                 \
        } while (0)

    // ---- prologue: stage chunk 0 into buf 0 ----
    STAGE_LOAD(0);
    asm volatile("s_waitcnt vmcnt(0)" ::: "memory");
    STAGE_WRITE(0);

    // ---- K loop: 8 chunks of 64, ONE barrier per chunk ----
    #pragma unroll
    for (int kc = 0; kc < NKC; ++kc) {
        BAR();   // buf[kc&1] visible to all; buf[(kc+1)&1] free to write

        // 1) B fragments (L2-resident, 4 loads/wave) -- oldest in VMEM queue
        bf16x8 bfr[2][2];
        #pragma unroll
        for (int s = 0; s < 2; ++s)
            #pragma unroll
            for (int j = 0; j < 2; ++j)
                bfr[s][j] = *reinterpret_cast<const bf16x8*>(
                    Wb + (size_t)(n0 + j * 16 + l16) * K_DIM + kc * KC + s * 32 + g * 8);
        __builtin_amdgcn_sched_barrier(0);   // pin: B-loads stay above G-loads

        // 2) issue G loads for chunk kc+1 (newest; fly across compute)
        if (kc + 1 < NKC) STAGE_LOAD(kc + 1);
        __builtin_amdgcn_sched_barrier(0);   // pin: G-loads stay above compute

        // 3) compute chunk kc from LDS buf kc&1 (A-frag = 1 ds_read_b128;
        //    compiler's B-use wait = counted vmcnt, G stays in flight)
        const int bufb = (kc & 1) * 16384;
        __builtin_amdgcn_s_setprio(1);
        #pragma unroll
        for (int s = 0; s < 2; ++s) {
            #pragma unroll
            for (int i = 0; i < 8; ++i) {
                const int row = i * 16 + l16;
                bf16x8 av = *reinterpret_cast<const bf16x8*>(
                    smem + bufb + row * 128 + ((s * 64 + g * 16) ^ ((row & 7) << 4)));
                #pragma unroll
                for (int j = 0; j < 2; ++j)
                    acc[i][j] = __builtin_amdgcn_mfma_f32_16x16x32_bf16(
                        av, bfr[s][j], acc[i][j], 0, 0, 0);
            }
        }
        __builtin_amdgcn_s_setprio(0);

        // 4) convert + write the prefetched chunk (loads had whole compute)
        if (kc + 1 < NKC) {
            asm volatile("s_waitcnt vmcnt(0)" ::: "memory");
            STAGE_WRITE((kc + 1) & 1);
        }
    }
    #undef STAGE_LOAD
    #undef STAGE_WRITE

    // ---- bias + tanh in regs ----
    // D layout: col = lane&15, row(within 16x16) = (lane>>4)*4 + r
    #pragma unroll
    for (int j = 0; j < 2; ++j) {
        const float bj = bias[n0 + j * 16 + l16];
        #pragma unroll
        for (int i = 0; i < 8; ++i)
            #pragma unroll
            for (int r = 0; r < 4; ++r)
                acc[i][j][r] = fast_tanh(acc[i][j][r] + bj);
    }

    // ---- in-register segmented product, per 64-row half h ----
    // Virtual 64-row group vb = bid*2 + h keeps partial/pass2 layout stable.
    #pragma unroll
    for (int h = 0; h < 2; ++h) {
        const int vb     = bid * 2 + h;
        const int myseg  = seg[m0 + h * 64 + lane];
        const int prevsg = (lane == 0) ? (myseg ^ 1) : seg[m0 + h * 64 + lane - 1];
        uint64_t m = __ballot(myseg != prevsg);              // run-start bits

        while (m) {
            const int start = (int)__builtin_ctzll(m);
            m &= m - 1;
            const int end = m ? (int)__builtin_ctzll(m) : 64;
            const int s   = __shfl(myseg, start);            // run's segment id

            float p[2] = {1.0f, 1.0f};
            #pragma unroll
            for (int i2 = 0; i2 < 4; ++i2)
                #pragma unroll
                for (int r = 0; r < 4; ++r) {
                    const int row = i2 * 16 + g * 4 + r;     // row within half
                    const bool in = (row >= start) && (row < end);
                    #pragma unroll
                    for (int j = 0; j < 2; ++j)
                        p[j] *= in ? acc[h * 4 + i2][j][r] : 1.0f;
                }
            #pragma unroll
            for (int j = 0; j < 2; ++j) {
                p[j] *= __shfl_xor(p[j], 16);
                p[j] *= __shfl_xor(p[j], 32);
            }
            if (g == 0) {
                #pragma unroll
                for (int j = 0; j < 2; ++j) {
                    const int col = n0 + j * 16 + l16;
                    if (start == 0)
                        partial[(size_t)(vb * 2 + 0) * N_RANK + col] = p[j];
                    else if (end == 64)
                        partial[(size_t)(vb * 2 + 1) * N_RANK + col] = p[j];
                    else
                        out[(size_t)s * N_RANK + col] = p[j]; // interior: exclusive
                }
            }
        }
    }
}

// Kernel 3 (pass 2): combine boundary partials over 64-row groups (b = vb).
// Group b owns boundary segment s iff s first appears in group b. Interior
// segments were stored by pass 1; empty segments stay 1.0.
__global__ void pass2_kernel(const int* __restrict__ seg,
                             const float* __restrict__ partial,
                             float* __restrict__ out) {
    const int b   = blockIdx.x;
    const int col = threadIdx.x;      // 0..255
    const int sF    = seg[b * 64];
    const int sL    = seg[b * 64 + 63];
    const int prevL = (b == 0) ? -1 : seg[b * 64 - 1];

    if (prevL < sF) {                 // b owns its first segment
        float p = partial[(size_t)(b * 2 + 0) * N_RANK + col];
        for (int b2 = b + 1; b2 < NB64 && seg[b2 * 64] == sF; ++b2)
            p *= partial[(size_t)(b2 * 2 + 0) * N_RANK + col];
        out[(size_t)sF * N_RANK + col] = p;
    }
    if (sL != sF) {                   // b always owns sL when sL != sF
        float p = partial[(size_t)(b * 2 + 1) * N_RANK + col];
        for (int b2 = b + 1; b2 < NB64 && seg[b2 * 64] == sL; ++b2)
            p *= partial[(size_t)(b2 * 2 + 0) * N_RANK + col];
        out[(size_t)sL * N_RANK + col] = p;
    }
}

extern "C" void kernel_launch(void* const* d_in, const int* in_sizes, int n_in,
                              void* d_out, int out_size, void* d_ws, size_t ws_size,
                              hipStream_t stream) {
    const float* x   = (const float*)d_in[0];
    const float* W   = (const float*)d_in[1];
    const float* b   = (const float*)d_in[2];
    const int*   seg = (const int*)d_in[3];
    float*       out = (float*)d_out;
    __hip_bfloat16* Wb = (__hip_bfloat16*)d_ws;                       // 256 KB
    float* partial = (float*)((char*)d_ws + (1 << 20));               // 4 MB @ +1MB

    prep_kernel<<<(NSEG * N_RANK) / 256, 256, 0, stream>>>(W, Wb, out);
    fused_kernel<<<NBLK, 512, 0, stream>>>(x, Wb, b, seg, out, partial);
    pass2_kernel<<<NB64, 256, 0, stream>>>(seg, partial, out);
}

// Round 22
// 78.058 us; speedup vs baseline: 1.1176x; 1.0391x over previous
//
#include <hip/hip_runtime.h>
#include <hip/hip_bf16.h>
#include <stdint.h>

// Problem constants (from reference)
#define M_TOTAL 131072
#define K_DIM   512
#define N_RANK  256
#define NSEG    1024
#define KC      64              // k-chunk staged in LDS (64 bf16 per row)
#define NKC     (K_DIM / KC)    // 8
#define BM      128             // rows per block
#define NBLK    (M_TOTAL / BM)  // 1024 fused blocks
#define NB64    (M_TOTAL / 64)  // 2048 virtual 64-row groups (pass2 granularity)

typedef __attribute__((ext_vector_type(8))) short bf16x8;
typedef __attribute__((ext_vector_type(4))) float f32x4;

// Raw barrier: lgkmcnt(0) makes my ds_writes visible, vmcnt NOT drained.
#define BAR() do { \
    asm volatile("s_waitcnt lgkmcnt(0)" ::: "memory"); \
    __builtin_amdgcn_s_barrier(); \
} while (0)

__device__ inline short f2b(float f) {
    __hip_bfloat16 h = __float2bfloat16(f);
    return __builtin_bit_cast(short, h);
}

// fast tanh: t = sign(z) * (1 - 2/(e^{2|z|}+1))
__device__ inline float fast_tanh(float z) {
    float e = __expf(2.0f * fabsf(z));
    return copysignf(1.0f - 2.0f / (e + 1.0f), z);
}

// Kernel 1: init out to 1.0 (segment_prod identity for empty segments)
//           + convert W to bf16 in ws
__global__ void prep_kernel(const float* __restrict__ W,
                            __hip_bfloat16* __restrict__ Wb,
                            float* __restrict__ out) {
    int i = blockIdx.x * 256 + threadIdx.x;
    out[i] = 1.0f;
    if (i < N_RANK * K_DIM) Wb[i] = __float2bfloat16(W[i]);
}

// Kernel 2 (pass 1): fused GEMM + bias + tanh + in-register segmented product.
//
// R22 = R19 schedule with TWO chunks per barrier via 4-deep LDS rotation
// (buf = chunk & 3, 4 x 16 KB = 64 KB; 2 blocks/CU = 128 KB <= 160 KB).
// Barriers 8 -> 4 at constant KC=64 (R18's KC=128 barrier-halving regressed
// by serializing two full stage phases; this keeps the proven per-chunk
// sub-schedule byte-identical). Safety: iteration j writes chunks kk+2,kk+3
// into buffers whose previous chunks (kk-2,kk-1) were computed in iteration
// j-1, with the start-of-j barrier intervening -- double-barrier separation.
//
// Structure pins (measured R1-R21): 8-wave col-slice is the ONLY geometry
// fitting the (512,4) 128-reg cap (R13/R14/R17 spilled); KC=64, BM=128;
// bf16 cvt ONCE at stage-write (R12); B-loads oldest -> counted B-use wait,
// G-loads newest -> fly over compute (R9); mid-chunk G-drain free (R16);
// de-phasing hurts L2 (R20); setprio ~free (R19).
__launch_bounds__(512, 4)   // reg cap 128; spill canary = WRITE_SIZE balloon
__global__ void fused_kernel(const float* __restrict__ x,
                             const __hip_bfloat16* __restrict__ Wb,
                             const float* __restrict__ bias,
                             const int* __restrict__ seg,
                             float* __restrict__ out,
                             float* __restrict__ partial) {
    const int tid  = threadIdx.x;
    const int wave = tid >> 6;        // 0..7 = column-slice
    const int lane = tid & 63;
    const int l16  = lane & 15;
    const int g    = lane >> 4;       // 0..3 (k-group / row-group)
    const int bid  = blockIdx.x;
    const int m0   = bid * BM;
    const int n0   = wave * 32;

    // LDS: A quad-buffer, 4 x (128 rows x 128B bf16) = 64 KB.
    __shared__ alignas(16) char smem[65536];

    // ---- staging geometry: thread covers one 16B f32 slot, 4 slabs ----
    const int srow = tid >> 4;        // 0..31
    const int sc16 = tid & 15;

    f32x4 acc[8][2] = {};             // [m-frag][n-frag]
    f32x4 sg[4];                      // staged f32 (reused per half-iteration)

    #define STAGE_LOAD(kc_)                                                   \
        do {                                                                  \
            _Pragma("unroll")                                                 \
            for (int it = 0; it < 4; ++it)                                    \
                sg[it] = *reinterpret_cast<const f32x4*>(                     \
                    x + (size_t)(m0 + it * 32 + srow) * K_DIM + (kc_) * KC + sc16 * 4); \
        } while (0)

    #define STAGE_WRITE(buf_)                                                 \
        do {                                                                  \
            _Pragma("unroll")                                                 \
            for (int it = 0; it < 4; ++it) {                                  \
                const int row = it * 32 + srow;                               \
                short4 p;                                                     \
                p.x = f2b(sg[it][0]); p.y = f2b(sg[it][1]);                   \
                p.z = f2b(sg[it][2]); p.w = f2b(sg[it][3]);                   \
                *reinterpret_cast<short4*>(smem + (buf_) * 16384 + row * 128  \
                    + ((sc16 * 8) ^ ((row & 7) << 4))) = p;                   \
            }                                                                 \
        } while (0)

    #define B_LOAD(c_)                                                        \
        do {                                                                  \
            _Pragma("unroll")                                                 \
            for (int s = 0; s < 2; ++s)                                       \
                _Pragma("unroll")                                             \
                for (int j = 0; j < 2; ++j)                                   \
                    bfr[s][j] = *reinterpret_cast<const bf16x8*>(             \
                        Wb + (size_t)(n0 + j * 16 + l16) * K_DIM + (c_) * KC  \
                           + s * 32 + g * 8);                                 \
        } while (0)

    #define COMPUTE(c_)                                                       \
        do {                                                                  \
            const int bufb = ((c_) & 3) * 16384;                              \
            __builtin_amdgcn_s_setprio(1);                                    \
            _Pragma("unroll")                                                 \
            for (int s = 0; s < 2; ++s) {                                     \
                _Pragma("unroll")                                             \
                for (int i = 0; i < 8; ++i) {                                 \
                    const int row = i * 16 + l16;                             \
                    bf16x8 av = *reinterpret_cast<const bf16x8*>(             \
                        smem + bufb + row * 128 +                             \
                        ((s * 64 + g * 16) ^ ((row & 7) << 4)));              \
                    _Pragma("unroll")                                         \
                    for (int j = 0; j < 2; ++j)                               \
                        acc[i][j] = __builtin_amdgcn_mfma_f32_16x16x32_bf16(  \
                            av, bfr[s][j], acc[i][j], 0, 0, 0);               \
                }                                                             \
            }                                                                 \
            __builtin_amdgcn_s_setprio(0);                                    \
        } while (0)

    // ---- prologue: stage chunks 0,1 into buffers 0,1 ----
    STAGE_LOAD(0);
    asm volatile("s_waitcnt vmcnt(0)" ::: "memory");
    STAGE_WRITE(0);
    STAGE_LOAD(1);
    asm volatile("s_waitcnt vmcnt(0)" ::: "memory");
    STAGE_WRITE(1);

    // ---- K loop: 8 chunks, TWO per barrier, 4-deep buffer rotation ----
    #pragma unroll
    for (int kk = 0; kk < NKC; kk += 2) {
        bf16x8 bfr[2][2];
        BAR();   // chunks kk,kk+1 visible; buffers (kk+2)&3,(kk+3)&3 free

        // --- chunk kk ---
        B_LOAD(kk);                          // oldest -> counted B-use wait
        __builtin_amdgcn_sched_barrier(0);
        if (kk + 2 < NKC) STAGE_LOAD(kk + 2);   // newest; fly over compute
        __builtin_amdgcn_sched_barrier(0);
        COMPUTE(kk);
        if (kk + 2 < NKC) {
            asm volatile("s_waitcnt vmcnt(0)" ::: "memory");  // free (R16)
            STAGE_WRITE((kk + 2) & 3);
        }

        // --- chunk kk+1 (same sub-schedule, registers reused) ---
        B_LOAD(kk + 1);
        __builtin_amdgcn_sched_barrier(0);
        if (kk + 3 < NKC) STAGE_LOAD(kk + 3);
        __builtin_amdgcn_sched_barrier(0);
        COMPUTE(kk + 1);
        if (kk + 3 < NKC) {
            asm volatile("s_waitcnt vmcnt(0)" ::: "memory");
            STAGE_WRITE((kk + 3) & 3);
        }
    }
    #undef STAGE_LOAD
    #undef STAGE_WRITE
    #undef B_LOAD
    #undef COMPUTE

    // ---- bias + tanh in regs ----
    // D layout: col = lane&15, row(within 16x16) = (lane>>4)*4 + r
    #pragma unroll
    for (int j = 0; j < 2; ++j) {
        const float bj = bias[n0 + j * 16 + l16];
        #pragma unroll
        for (int i = 0; i < 8; ++i)
            #pragma unroll
            for (int r = 0; r < 4; ++r)
                acc[i][j][r] = fast_tanh(acc[i][j][r] + bj);
    }

    // ---- in-register segmented product, per 64-row half h ----
    // Virtual 64-row group vb = bid*2 + h keeps partial/pass2 layout stable.
    #pragma unroll
    for (int h = 0; h < 2; ++h) {
        const int vb     = bid * 2 + h;
        const int myseg  = seg[m0 + h * 64 + lane];
        const int prevsg = (lane == 0) ? (myseg ^ 1) : seg[m0 + h * 64 + lane - 1];
        uint64_t m = __ballot(myseg != prevsg);              // run-start bits

        while (m) {
            const int start = (int)__builtin_ctzll(m);
            m &= m - 1;
            const int end = m ? (int)__builtin_ctzll(m) : 64;
            const int s   = __shfl(myseg, start);            // run's segment id

            float p[2] = {1.0f, 1.0f};
            #pragma unroll
            for (int i2 = 0; i2 < 4; ++i2)
                #pragma unroll
                for (int r = 0; r < 4; ++r) {
                    const int row = i2 * 16 + g * 4 + r;     // row within half
                    const bool in = (row >= start) && (row < end);
                    #pragma unroll
                    for (int j = 0; j < 2; ++j)
                        p[j] *= in ? acc[h * 4 + i2][j][r] : 1.0f;
                }
            #pragma unroll
            for (int j = 0; j < 2; ++j) {
                p[j] *= __shfl_xor(p[j], 16);
                p[j] *= __shfl_xor(p[j], 32);
            }
            if (g == 0) {
                #pragma unroll
                for (int j = 0; j < 2; ++j) {
                    const int col = n0 + j * 16 + l16;
                    if (start == 0)
                        partial[(size_t)(vb * 2 + 0) * N_RANK + col] = p[j];
                    else if (end == 64)
                        partial[(size_t)(vb * 2 + 1) * N_RANK + col] = p[j];
                    else
                        out[(size_t)s * N_RANK + col] = p[j]; // interior: exclusive
                }
            }
        }
    }
}

// Kernel 3 (pass 2): combine boundary partials over 64-row groups (b = vb).
// Group b owns boundary segment s iff s first appears in group b. Interior
// segments were stored by pass 1; empty segments stay 1.0.
__global__ void pass2_kernel(const int* __restrict__ seg,
                             const float* __restrict__ partial,
                             float* __restrict__ out) {
    const int b   = blockIdx.x;
    const int col = threadIdx.x;      // 0..255
    const int sF    = seg[b * 64];
    const int sL    = seg[b * 64 + 63];
    const int prevL = (b == 0) ? -1 : seg[b * 64 - 1];

    if (prevL < sF) {                 // b owns its first segment
        float p = partial[(size_t)(b * 2 + 0) * N_RANK + col];
        for (int b2 = b + 1; b2 < NB64 && seg[b2 * 64] == sF; ++b2)
            p *= partial[(size_t)(b2 * 2 + 0) * N_RANK + col];
        out[(size_t)sF * N_RANK + col] = p;
    }
    if (sL != sF) {                   // b always owns sL when sL != sF
        float p = partial[(size_t)(b * 2 + 1) * N_RANK + col];
        for (int b2 = b + 1; b2 < NB64 && seg[b2 * 64] == sL; ++b2)
            p *= partial[(size_t)(b2 * 2 + 0) * N_RANK + col];
        out[(size_t)sL * N_RANK + col] = p;
    }
}

extern "C" void kernel_launch(void* const* d_in, const int* in_sizes, int n_in,
                              void* d_out, int out_size, void* d_ws, size_t ws_size,
                              hipStream_t stream) {
    const float* x   = (const float*)d_in[0];
    const float* W   = (const float*)d_in[1];
    const float* b   = (const float*)d_in[2];
    const int*   seg = (const int*)d_in[3];
    float*       out = (float*)d_out;
    __hip_bfloat16* Wb = (__hip_bfloat16*)d_ws;                       // 256 KB
    float* partial = (float*)((char*)d_ws + (1 << 20));               // 4 MB @ +1MB

    prep_kernel<<<(NSEG * N_RANK) / 256, 256, 0, stream>>>(W, Wb, out);
    fused_kernel<<<NBLK, 512, 0, stream>>>(x, Wb, b, seg, out, partial);
    pass2_kernel<<<NB64, 256, 0, stream>>>(seg, partial, out);
}